// Round 1
// baseline (306.572 us; speedup 1.0000x reference)
//
#include <hip/hip_runtime.h>

// Problem dims
constexpr int Bb = 64;     // batch
constexpr int Tt = 256;    // timesteps
constexpr int Dd = 512;    // input dim (K)
constexpr int Hh = 1024;   // hidden (N)
constexpr int Mm = Bb * Tt;  // 16384 GEMM rows

// GEMM tiling
#define BM 128
#define BN 128
#define BK 16
#define BMP 132  // padded LDS leading dim

// pre[m][h] = sum_d x[m][d] * W_in[h][d] + b_in[h]
// A = x [M][K] row-major, B = W_in [N][K] row-major (NT GEMM, both K-contiguous)
__global__ __launch_bounds__(256) void gemm_pre(const float* __restrict__ x,
                                                const float* __restrict__ Win,
                                                const float* __restrict__ bin,
                                                float* __restrict__ pre) {
    __shared__ float As[BK][BMP];
    __shared__ float Bs[BK][BMP];

    const int tid = threadIdx.x;
    const int m0 = blockIdx.y * BM;
    const int n0 = blockIdx.x * BN;
    const int tx = tid & 15;
    const int ty = tid >> 4;

    float acc[8][8];
#pragma unroll
    for (int i = 0; i < 8; ++i)
#pragma unroll
        for (int j = 0; j < 8; ++j) acc[i][j] = 0.0f;

    const float* Aptr = x + (size_t)m0 * Dd;
    const float* Bptr = Win + (size_t)n0 * Dd;

    for (int k0 = 0; k0 < Dd; k0 += BK) {
        // Stage 128x16 tiles of A and B into LDS (transposed to [BK][BM]).
        // 512 float4 loads per matrix, 2 per thread.
#pragma unroll
        for (int i = 0; i < 2; ++i) {
            const int lin = tid + i * 256;      // 0..511
            const int row = lin >> 2;           // 0..127
            const int kq  = (lin & 3) << 2;     // 0,4,8,12
            const float4 av = *(const float4*)(Aptr + (size_t)row * Dd + k0 + kq);
            const float4 bv = *(const float4*)(Bptr + (size_t)row * Dd + k0 + kq);
            As[kq + 0][row] = av.x;
            As[kq + 1][row] = av.y;
            As[kq + 2][row] = av.z;
            As[kq + 3][row] = av.w;
            Bs[kq + 0][row] = bv.x;
            Bs[kq + 1][row] = bv.y;
            Bs[kq + 2][row] = bv.z;
            Bs[kq + 3][row] = bv.w;
        }
        __syncthreads();

#pragma unroll
        for (int kk = 0; kk < BK; ++kk) {
            const float4 a0 = *(const float4*)&As[kk][ty * 4];
            const float4 a1 = *(const float4*)&As[kk][ty * 4 + 64];
            const float4 b0 = *(const float4*)&Bs[kk][tx * 4];
            const float4 b1 = *(const float4*)&Bs[kk][tx * 4 + 64];
            const float a[8] = {a0.x, a0.y, a0.z, a0.w, a1.x, a1.y, a1.z, a1.w};
            const float b[8] = {b0.x, b0.y, b0.z, b0.w, b1.x, b1.y, b1.z, b1.w};
#pragma unroll
            for (int i = 0; i < 8; ++i)
#pragma unroll
                for (int j = 0; j < 8; ++j) acc[i][j] += a[i] * b[j];
        }
        __syncthreads();
    }

    // Epilogue: add bias, store float4
#pragma unroll
    for (int i = 0; i < 8; ++i) {
        const int m = m0 + ((i < 4) ? (ty * 4 + i) : (64 + ty * 4 + i - 4));
#pragma unroll
        for (int half = 0; half < 2; ++half) {
            const int n = n0 + tx * 4 + half * 64;
            float4 v;
            v.x = acc[i][half * 4 + 0] + bin[n + 0];
            v.y = acc[i][half * 4 + 1] + bin[n + 1];
            v.z = acc[i][half * 4 + 2] + bin[n + 2];
            v.w = acc[i][half * 4 + 3] + bin[n + 3];
            *(float4*)(pre + (size_t)m * Hh + n) = v;
        }
    }
}

// ALIF scan: one thread per (b,h). mem = 0.9*mem + p - adapt; spk = mem>0;
// adapt += 0.1*spk; mem -= spk. Accumulate spike count, fuse readout weight,
// block-reduce to one partial per (b, h-chunk).
__global__ __launch_bounds__(256) void alif_scan(const float* __restrict__ pre,
                                                 const float* __restrict__ Wout,
                                                 float* __restrict__ partials) {
    const int h = blockIdx.x * 256 + threadIdx.x;
    const int b = blockIdx.y;
    const float* p = pre + (size_t)b * Tt * Hh + h;

    float mem = 0.0f, adapt = 0.0f, cnt = 0.0f;
#pragma unroll 4
    for (int t = 0; t < Tt; ++t) {
        const float v = p[(size_t)t * Hh];
        mem = 0.9f * mem + v - adapt;
        const float spk = (mem > 0.0f) ? 1.0f : 0.0f;
        adapt += 0.1f * spk;
        mem -= spk;
        cnt += spk;
    }

    __shared__ float red[256];
    red[threadIdx.x] = cnt * Wout[h];
    __syncthreads();
#pragma unroll
    for (int s = 128; s > 0; s >>= 1) {
        if (threadIdx.x < s) red[threadIdx.x] += red[threadIdx.x + s];
        __syncthreads();
    }
    if (threadIdx.x == 0) partials[b * gridDim.x + blockIdx.x] = red[0];
}

__global__ void finalize(const float* __restrict__ partials,
                         const float* __restrict__ bout,
                         float* __restrict__ out, int nchunks) {
    const int b = threadIdx.x;  // 64 threads
    float s = 0.0f;
    for (int c = 0; c < nchunks; ++c) s += partials[b * nchunks + c];
    out[b] = s * (1.0f / (float)Tt) + bout[0];
}

extern "C" void kernel_launch(void* const* d_in, const int* in_sizes, int n_in,
                              void* d_out, int out_size, void* d_ws, size_t ws_size,
                              hipStream_t stream) {
    const float* x    = (const float*)d_in[0];  // [B,T,D]
    const float* Win  = (const float*)d_in[1];  // [H,D]
    const float* bin  = (const float*)d_in[2];  // [H]
    const float* Wout = (const float*)d_in[3];  // [1,H]
    const float* bout = (const float*)d_in[4];  // [1]
    float* out = (float*)d_out;                 // [B,1]

    float* pre = (float*)d_ws;  // [M, H] = 64 MiB
    float* partials = (float*)((char*)d_ws + (size_t)Mm * Hh * sizeof(float));

    dim3 g1(Hh / BN, Mm / BM);  // (8, 128)
    gemm_pre<<<g1, 256, 0, stream>>>(x, Win, bin, pre);

    dim3 g2(Hh / 256, Bb);  // (4, 64)
    alif_scan<<<g2, 256, 0, stream>>>(pre, Wout, partials);

    finalize<<<1, 64, 0, stream>>>(partials, bout, out, Hh / 256);
}

// Round 2
// 229.834 us; speedup vs baseline: 1.3339x; 1.3339x over previous
//
#include <hip/hip_runtime.h>

// Problem dims
constexpr int Bb = 64;     // batch
constexpr int Tt = 256;    // timesteps
constexpr int Dd = 512;    // input dim (K)
constexpr int Hh = 1024;   // hidden (N)
constexpr int Mm = Bb * Tt;  // 16384 GEMM rows

typedef _Float16 half8 __attribute__((ext_vector_type(8)));
typedef _Float16 half4v __attribute__((ext_vector_type(4)));
typedef float floatx16 __attribute__((ext_vector_type(16)));

#define GPTR(x) ((const __attribute__((address_space(1))) void*)(x))
#define LPTR(x) ((__attribute__((address_space(3))) void*)(x))

// ---------------------------------------------------------------------------
// Kernel 1: fp32 -> f16 hi/lo split. a ~= hi + lo * 2^-12 (lo stored *4096 to
// stay in f16 normal range). Processes x then W_in, float4-grained.
// ---------------------------------------------------------------------------
__global__ __launch_bounds__(256) void convert_f16x2(const float* __restrict__ x,
                                                     const float* __restrict__ Win,
                                                     _Float16* __restrict__ xh,
                                                     _Float16* __restrict__ xl,
                                                     _Float16* __restrict__ wh,
                                                     _Float16* __restrict__ wl) {
    constexpr int XN4 = Mm * Dd / 4;  // 2097152
    const int i = blockIdx.x * 256 + threadIdx.x;
    const float4* src;
    _Float16 *dh, *dl;
    int j;
    if (i < XN4) { src = (const float4*)x; j = i; dh = xh; dl = xl; }
    else { src = (const float4*)Win; j = i - XN4; dh = wh; dl = wl; }
    const float4 v = src[j];
    const float va[4] = {v.x, v.y, v.z, v.w};
    half4v h, l;
#pragma unroll
    for (int q = 0; q < 4; ++q) {
        const _Float16 hi = (_Float16)va[q];
        h[q] = hi;
        l[q] = (_Float16)((va[q] - (float)hi) * 4096.0f);
    }
    *(half4v*)(dh + (size_t)j * 4) = h;
    *(half4v*)(dl + (size_t)j * 4) = l;
}

// ---------------------------------------------------------------------------
// Kernel 2: split-precision MFMA GEMM. pre[m][n] = sum_k x[m][k]*W[n][k] + b[n]
// Tile 128x128, BK=16, 4 waves each computing 64x64 via 2x2 of 32x32x16 f16
// MFMA. Two accumulators: hh and cross (Ah*Bl + Al*Bh, folded *2^-12 at end).
// LDS tiles stored chunk-major ([kpart][row] of 16B chunks) so both the
// global_load_lds staging (lane-contiguous dest) and the ds_read_b128 frag
// reads (16B-stride contiguous) are conflict-free.
// ---------------------------------------------------------------------------
__global__ __launch_bounds__(256) void gemm_f16x2(const _Float16* __restrict__ xh,
                                                  const _Float16* __restrict__ xl,
                                                  const _Float16* __restrict__ wh,
                                                  const _Float16* __restrict__ wl,
                                                  const float* __restrict__ bin,
                                                  float* __restrict__ pre) {
    // 4 tiles (Ah, Al, Bh, Bl), each 128 rows x 16 k = 2048 halves = 4KB
    __shared__ _Float16 lds[4][2048];

    const int tid = threadIdx.x;
    const int m0 = blockIdx.y * 128;
    const int n0 = blockIdx.x * 128;

    const int lane = tid & 63;
    const int wave = tid >> 6;
    const int wm = (wave & 1) * 64;
    const int wn = (wave >> 1) * 64;
    const int lr = lane & 31;  // row within 32x32 tile
    const int lk = lane >> 5;  // k-part (0/1)

    floatx16 acc[2][2], accx[2][2];
#pragma unroll
    for (int mi = 0; mi < 2; ++mi)
#pragma unroll
        for (int ni = 0; ni < 2; ++ni)
#pragma unroll
            for (int r = 0; r < 16; ++r) { acc[mi][ni][r] = 0.0f; accx[mi][ni][r] = 0.0f; }

    // staging map: chunk c = tid in [0,256): kpart = c>>7, row = c&127.
    // LDS offset = c*8 halves (16B); global = row-major src + kpart*8 halves.
    const int sc_kp = tid >> 7;
    const int sc_row = tid & 127;

    for (int k0 = 0; k0 < Dd; k0 += 16) {
        const size_t aoff = (size_t)(m0 + sc_row) * Dd + k0 + sc_kp * 8;
        const size_t boff = (size_t)(n0 + sc_row) * Dd + k0 + sc_kp * 8;
        __builtin_amdgcn_global_load_lds(GPTR(xh + aoff), LPTR(&lds[0][tid * 8]), 16, 0, 0);
        __builtin_amdgcn_global_load_lds(GPTR(xl + aoff), LPTR(&lds[1][tid * 8]), 16, 0, 0);
        __builtin_amdgcn_global_load_lds(GPTR(wh + boff), LPTR(&lds[2][tid * 8]), 16, 0, 0);
        __builtin_amdgcn_global_load_lds(GPTR(wl + boff), LPTR(&lds[3][tid * 8]), 16, 0, 0);
        __syncthreads();

        half8 ah[2], al[2], bh[2], bl[2];
#pragma unroll
        for (int mi = 0; mi < 2; ++mi) {
            const int chunk = lk * 128 + wm + mi * 32 + lr;
            ah[mi] = *(const half8*)&lds[0][chunk * 8];
            al[mi] = *(const half8*)&lds[1][chunk * 8];
        }
#pragma unroll
        for (int ni = 0; ni < 2; ++ni) {
            const int chunk = lk * 128 + wn + ni * 32 + lr;
            bh[ni] = *(const half8*)&lds[2][chunk * 8];
            bl[ni] = *(const half8*)&lds[3][chunk * 8];
        }
#pragma unroll
        for (int mi = 0; mi < 2; ++mi)
#pragma unroll
            for (int ni = 0; ni < 2; ++ni) {
                acc[mi][ni]  = __builtin_amdgcn_mfma_f32_32x32x16_f16(ah[mi], bh[ni], acc[mi][ni], 0, 0, 0);
                accx[mi][ni] = __builtin_amdgcn_mfma_f32_32x32x16_f16(ah[mi], bl[ni], accx[mi][ni], 0, 0, 0);
                accx[mi][ni] = __builtin_amdgcn_mfma_f32_32x32x16_f16(al[mi], bh[ni], accx[mi][ni], 0, 0, 0);
            }
        __syncthreads();
    }

    // Epilogue: C/D layout (32x32): col = lane&31, row = (r&3) + 8*(r>>2) + 4*(lane>>5)
#pragma unroll
    for (int mi = 0; mi < 2; ++mi)
#pragma unroll
        for (int ni = 0; ni < 2; ++ni)
#pragma unroll
            for (int r = 0; r < 16; ++r) {
                const int row = (r & 3) + 8 * (r >> 2) + 4 * lk;
                const int m = m0 + wm + mi * 32 + row;
                const int n = n0 + wn + ni * 32 + lr;
                pre[(size_t)m * Hh + n] =
                    acc[mi][ni][r] + accx[mi][ni][r] * (1.0f / 4096.0f) + bin[n];
            }
}

// ---------------------------------------------------------------------------
// Fallback fp32 SIMT GEMM (proven in round 1) in case ws is too small.
// ---------------------------------------------------------------------------
#define BK 16
#define BMP 132
__global__ __launch_bounds__(256) void gemm_pre(const float* __restrict__ x,
                                                const float* __restrict__ Win,
                                                const float* __restrict__ bin,
                                                float* __restrict__ pre) {
    __shared__ float As[BK][BMP];
    __shared__ float Bs[BK][BMP];
    const int tid = threadIdx.x;
    const int m0 = blockIdx.y * 128;
    const int n0 = blockIdx.x * 128;
    const int tx = tid & 15;
    const int ty = tid >> 4;
    float acc[8][8];
#pragma unroll
    for (int i = 0; i < 8; ++i)
#pragma unroll
        for (int j = 0; j < 8; ++j) acc[i][j] = 0.0f;
    const float* Aptr = x + (size_t)m0 * Dd;
    const float* Bptr = Win + (size_t)n0 * Dd;
    for (int k0 = 0; k0 < Dd; k0 += BK) {
#pragma unroll
        for (int i = 0; i < 2; ++i) {
            const int lin = tid + i * 256;
            const int row = lin >> 2;
            const int kq = (lin & 3) << 2;
            const float4 av = *(const float4*)(Aptr + (size_t)row * Dd + k0 + kq);
            const float4 bv = *(const float4*)(Bptr + (size_t)row * Dd + k0 + kq);
            As[kq + 0][row] = av.x; As[kq + 1][row] = av.y;
            As[kq + 2][row] = av.z; As[kq + 3][row] = av.w;
            Bs[kq + 0][row] = bv.x; Bs[kq + 1][row] = bv.y;
            Bs[kq + 2][row] = bv.z; Bs[kq + 3][row] = bv.w;
        }
        __syncthreads();
#pragma unroll
        for (int kk = 0; kk < BK; ++kk) {
            const float4 a0 = *(const float4*)&As[kk][ty * 4];
            const float4 a1 = *(const float4*)&As[kk][ty * 4 + 64];
            const float4 b0 = *(const float4*)&Bs[kk][tx * 4];
            const float4 b1 = *(const float4*)&Bs[kk][tx * 4 + 64];
            const float a[8] = {a0.x, a0.y, a0.z, a0.w, a1.x, a1.y, a1.z, a1.w};
            const float b[8] = {b0.x, b0.y, b0.z, b0.w, b1.x, b1.y, b1.z, b1.w};
#pragma unroll
            for (int i = 0; i < 8; ++i)
#pragma unroll
                for (int j = 0; j < 8; ++j) acc[i][j] += a[i] * b[j];
        }
        __syncthreads();
    }
#pragma unroll
    for (int i = 0; i < 8; ++i) {
        const int m = m0 + ((i < 4) ? (ty * 4 + i) : (64 + ty * 4 + i - 4));
#pragma unroll
        for (int half = 0; half < 2; ++half) {
            const int n = n0 + tx * 4 + half * 64;
            float4 v;
            v.x = acc[i][half * 4 + 0] + bin[n + 0];
            v.y = acc[i][half * 4 + 1] + bin[n + 1];
            v.z = acc[i][half * 4 + 2] + bin[n + 2];
            v.w = acc[i][half * 4 + 3] + bin[n + 3];
            *(float4*)(pre + (size_t)m * Hh + n) = v;
        }
    }
}

// ---------------------------------------------------------------------------
// Kernel 3: ALIF scan, 16-deep software-pipelined loads.
// ---------------------------------------------------------------------------
__global__ __launch_bounds__(256) void alif_scan(const float* __restrict__ pre,
                                                 const float* __restrict__ Wout,
                                                 float* __restrict__ partials) {
    const int h = blockIdx.x * 256 + threadIdx.x;
    const int b = blockIdx.y;
    const float* p = pre + (size_t)b * Tt * Hh + h;

    float buf[16];
#pragma unroll
    for (int j = 0; j < 16; ++j) buf[j] = p[(size_t)j * Hh];

    float mem = 0.0f, adapt = 0.0f, cnt = 0.0f;
    for (int t0 = 0; t0 < Tt; t0 += 16) {
        float cur[16];
#pragma unroll
        for (int j = 0; j < 16; ++j) cur[j] = buf[j];
        if (t0 + 16 < Tt) {
#pragma unroll
            for (int j = 0; j < 16; ++j) buf[j] = p[(size_t)(t0 + 16 + j) * Hh];
        }
#pragma unroll
        for (int j = 0; j < 16; ++j) {
            mem = 0.9f * mem + cur[j] - adapt;
            const float spk = (mem > 0.0f) ? 1.0f : 0.0f;
            adapt += 0.1f * spk;
            mem -= spk;
            cnt += spk;
        }
    }

    __shared__ float red[256];
    red[threadIdx.x] = cnt * Wout[h];
    __syncthreads();
#pragma unroll
    for (int s = 128; s > 0; s >>= 1) {
        if (threadIdx.x < s) red[threadIdx.x] += red[threadIdx.x + s];
        __syncthreads();
    }
    if (threadIdx.x == 0) partials[b * gridDim.x + blockIdx.x] = red[0];
}

__global__ void finalize(const float* __restrict__ partials,
                         const float* __restrict__ bout,
                         float* __restrict__ out, int nchunks) {
    const int b = threadIdx.x;
    float s = 0.0f;
    for (int c = 0; c < nchunks; ++c) s += partials[b * nchunks + c];
    out[b] = s * (1.0f / (float)Tt) + bout[0];
}

extern "C" void kernel_launch(void* const* d_in, const int* in_sizes, int n_in,
                              void* d_out, int out_size, void* d_ws, size_t ws_size,
                              hipStream_t stream) {
    const float* x    = (const float*)d_in[0];
    const float* Win  = (const float*)d_in[1];
    const float* bin  = (const float*)d_in[2];
    const float* Wout = (const float*)d_in[3];
    const float* bout = (const float*)d_in[4];
    float* out = (float*)d_out;

    // ws layout
    const size_t pre_bytes = (size_t)Mm * Hh * 4;      // 64 MiB
    const size_t xh_bytes  = (size_t)Mm * Dd * 2;      // 32 MiB
    const size_t wh_bytes  = (size_t)Hh * Dd * 2;      // 1 MiB
    float* pre = (float*)d_ws;

    const size_t need = pre_bytes + 2 * xh_bytes + 2 * wh_bytes + 4096;
    if (ws_size >= need) {
        char* base = (char*)d_ws + pre_bytes;
        _Float16* xh = (_Float16*)base;
        _Float16* xl = (_Float16*)(base + xh_bytes);
        _Float16* wh = (_Float16*)(base + 2 * xh_bytes);
        _Float16* wl = (_Float16*)(base + 2 * xh_bytes + wh_bytes);
        float* partials = (float*)(base + 2 * xh_bytes + 2 * wh_bytes);

        const int nconv = (Mm * Dd + Hh * Dd) / 4;  // float4 chunks
        convert_f16x2<<<nconv / 256, 256, 0, stream>>>(x, Win, xh, xl, wh, wl);

        dim3 g1(Hh / 128, Mm / 128);  // (8, 128)
        gemm_f16x2<<<g1, 256, 0, stream>>>(xh, xl, wh, wl, bin, pre);

        dim3 g2(Hh / 256, Bb);
        alif_scan<<<g2, 256, 0, stream>>>(pre, Wout, partials);
        finalize<<<1, 64, 0, stream>>>(partials, bout, out, Hh / 256);
    } else {
        float* partials = (float*)((char*)d_ws + pre_bytes);
        dim3 g1(Hh / 128, Mm / 128);
        gemm_pre<<<g1, 256, 0, stream>>>(x, Win, bin, pre);
        dim3 g2(Hh / 256, Bb);
        alif_scan<<<g2, 256, 0, stream>>>(pre, Wout, partials);
        finalize<<<1, 64, 0, stream>>>(partials, bout, out, Hh / 256);
    }
}

// Round 3
// 157.028 us; speedup vs baseline: 1.9523x; 1.4636x over previous
//
#include <hip/hip_runtime.h>

// Problem dims
constexpr int Bb = 64;     // batch
constexpr int Tt = 256;    // timesteps
constexpr int Dd = 512;    // input dim (K)
constexpr int Hh = 1024;   // hidden (N)
constexpr int Mm = Bb * Tt;  // 16384 GEMM rows

typedef _Float16 half8 __attribute__((ext_vector_type(8)));
typedef _Float16 half4v __attribute__((ext_vector_type(4)));
typedef float floatx16 __attribute__((ext_vector_type(16)));

#define GPTR(x) ((const __attribute__((address_space(1))) void*)(x))
#define LPTR(x) ((__attribute__((address_space(3))) void*)(x))

// ---------------------------------------------------------------------------
// Kernel 1: fp32 -> f16 hi/lo split, emitted CHUNK-TRANSPOSED: output element
// chunk g = kc*nrows + row holds src[row][kc*8 .. kc*8+8) as 8 halves (16B).
// This makes the GEMM's global_load_lds staging fully contiguous (1KB/instr).
// Handles both x (blockIdx.y < 256) and W_in (blockIdx.y >= 256).
// LDS tile 64x64, row stride 72 halves (144B, 16B-aligned for half8 access).
// ---------------------------------------------------------------------------
__global__ __launch_bounds__(256) void convert_t(const float* __restrict__ x,
                                                 const float* __restrict__ Win,
                                                 _Float16* __restrict__ xh,
                                                 _Float16* __restrict__ xl,
                                                 _Float16* __restrict__ wh,
                                                 _Float16* __restrict__ wl) {
    __shared__ _Float16 lh[64 * 72];
    __shared__ _Float16 ll[64 * 72];
    const int tid = threadIdx.x;
    const int k0 = blockIdx.x * 64;

    const float* src;
    _Float16 *dh, *dl;
    int nrows, m0;
    if (blockIdx.y < 256) {
        src = x; dh = xh; dl = xl; nrows = Mm; m0 = blockIdx.y * 64;
    } else {
        src = Win; dh = wh; dl = wl; nrows = Hh; m0 = (blockIdx.y - 256) * 64;
    }

#pragma unroll
    for (int i = 0; i < 4; ++i) {
        const int lin = tid + i * 256;
        const int row = lin >> 4;
        const int c4 = (lin & 15) * 4;
        const float4 v = *(const float4*)(src + (size_t)(m0 + row) * Dd + k0 + c4);
        const float va[4] = {v.x, v.y, v.z, v.w};
        half4v h, l;
#pragma unroll
        for (int q = 0; q < 4; ++q) {
            const _Float16 hi = (_Float16)va[q];
            h[q] = hi;
            l[q] = (_Float16)((va[q] - (float)hi) * 4096.0f);
        }
        *(half4v*)&lh[row * 72 + c4] = h;
        *(half4v*)&ll[row * 72 + c4] = l;
    }
    __syncthreads();
#pragma unroll
    for (int i = 0; i < 2; ++i) {
        const int lin = tid + i * 256;
        const int kc = lin >> 6;   // 0..7
        const int mm = lin & 63;
        const half8 h = *(const half8*)&lh[mm * 72 + kc * 8];
        const half8 l = *(const half8*)&ll[mm * 72 + kc * 8];
        const size_t g = (size_t)(k0 / 8 + kc) * nrows + m0 + mm;
        *(half8*)(dh + g * 8) = h;
        *(half8*)(dl + g * 8) = l;
    }
}

// ---------------------------------------------------------------------------
// Kernel 2: split-precision MFMA GEMM, BK=32, double-buffered LDS.
// pre[m][n] = sum_k x[m][k]*W[n][k] + b[n]; 3 MFMAs (hh + 2 cross) per k-step.
// LDS per buffer: 4 tiles (Ah,Al,Bh,Bl) x 128 rows x 32 halves (chunk-major
// [kp 0..3][row 0..127], 16B chunks) = 32KB; x2 buffers = 64KB.
// Staging: 8 global_load_lds/stage, each 1KB contiguous (transposed operands).
// Loads for stage s+1 issue before compute of stage s (latency hidden).
// ---------------------------------------------------------------------------
__global__ __launch_bounds__(256) void gemm_f16x2(const _Float16* __restrict__ xh,
                                                  const _Float16* __restrict__ xl,
                                                  const _Float16* __restrict__ wh,
                                                  const _Float16* __restrict__ wl,
                                                  const float* __restrict__ bin,
                                                  float* __restrict__ pre) {
    __shared__ _Float16 lds[2][4][4096];  // [buf][mat][512 chunks x 8 halves]

    const int tid = threadIdx.x;
    const int m0 = blockIdx.y * 128;
    const int n0 = blockIdx.x * 128;
    const int lane = tid & 63;
    const int wave = tid >> 6;
    const int wm = (wave & 1) * 64;
    const int wn = (wave >> 1) * 64;
    const int lr = lane & 31;
    const int lk = lane >> 5;

    floatx16 acc[2][2], accx[2][2];
#pragma unroll
    for (int mi = 0; mi < 2; ++mi)
#pragma unroll
        for (int ni = 0; ni < 2; ++ni)
#pragma unroll
            for (int r = 0; r < 16; ++r) { acc[mi][ni][r] = 0.0f; accx[mi][ni][r] = 0.0f; }

#define STAGE(buf, kc0)                                                              \
    do {                                                                             \
        _Pragma("unroll")                                                            \
        for (int i_ = 0; i_ < 2; ++i_) {                                             \
            const int c_ = tid + i_ * 256;                                           \
            const int kp_ = c_ >> 7;                                                 \
            const int row_ = c_ & 127;                                               \
            const size_t ga_ = ((size_t)((kc0) + kp_) * Mm + m0 + row_) * 8;         \
            const size_t gb_ = ((size_t)((kc0) + kp_) * Hh + n0 + row_) * 8;         \
            __builtin_amdgcn_global_load_lds(GPTR(xh + ga_), LPTR(&lds[buf][0][c_ * 8]), 16, 0, 0); \
            __builtin_amdgcn_global_load_lds(GPTR(xl + ga_), LPTR(&lds[buf][1][c_ * 8]), 16, 0, 0); \
            __builtin_amdgcn_global_load_lds(GPTR(wh + gb_), LPTR(&lds[buf][2][c_ * 8]), 16, 0, 0); \
            __builtin_amdgcn_global_load_lds(GPTR(wl + gb_), LPTR(&lds[buf][3][c_ * 8]), 16, 0, 0); \
        }                                                                            \
    } while (0)

    STAGE(0, 0);

    for (int s = 0; s < 16; ++s) {
        __syncthreads();  // drains stage-s loads; protects buf being overwritten
        if (s < 15) STAGE((s + 1) & 1, (s + 1) * 4);
        const int cur = s & 1;
#pragma unroll
        for (int s2 = 0; s2 < 2; ++s2) {
            half8 ah[2], al[2], bh[2], bl[2];
#pragma unroll
            for (int mi = 0; mi < 2; ++mi) {
                const int ci = (s2 * 2 + lk) * 128 + wm + mi * 32 + lr;
                ah[mi] = *(const half8*)&lds[cur][0][ci * 8];
                al[mi] = *(const half8*)&lds[cur][1][ci * 8];
            }
#pragma unroll
            for (int ni = 0; ni < 2; ++ni) {
                const int ci = (s2 * 2 + lk) * 128 + wn + ni * 32 + lr;
                bh[ni] = *(const half8*)&lds[cur][2][ci * 8];
                bl[ni] = *(const half8*)&lds[cur][3][ci * 8];
            }
#pragma unroll
            for (int mi = 0; mi < 2; ++mi)
#pragma unroll
                for (int ni = 0; ni < 2; ++ni) {
                    acc[mi][ni]  = __builtin_amdgcn_mfma_f32_32x32x16_f16(ah[mi], bh[ni], acc[mi][ni], 0, 0, 0);
                    accx[mi][ni] = __builtin_amdgcn_mfma_f32_32x32x16_f16(ah[mi], bl[ni], accx[mi][ni], 0, 0, 0);
                    accx[mi][ni] = __builtin_amdgcn_mfma_f32_32x32x16_f16(al[mi], bh[ni], accx[mi][ni], 0, 0, 0);
                }
        }
    }
#undef STAGE

    // Epilogue: C/D layout (32x32): col = lane&31, row = (r&3) + 8*(r>>2) + 4*(lane>>5)
    const float bv0 = bin[n0 + wn + lr];
    const float bv1 = bin[n0 + wn + 32 + lr];
#pragma unroll
    for (int mi = 0; mi < 2; ++mi)
#pragma unroll
        for (int ni = 0; ni < 2; ++ni) {
            const float bv = ni ? bv1 : bv0;
#pragma unroll
            for (int r = 0; r < 16; ++r) {
                const int row = (r & 3) + 8 * (r >> 2) + 4 * lk;
                const int m = m0 + wm + mi * 32 + row;
                const int n = n0 + wn + ni * 32 + lr;
                pre[(size_t)m * Hh + n] =
                    acc[mi][ni][r] + accx[mi][ni][r] * (1.0f / 4096.0f) + bv;
            }
        }
}

// ---------------------------------------------------------------------------
// Fallback fp32 SIMT GEMM (proven) in case ws is too small.
// ---------------------------------------------------------------------------
#define BK 16
#define BMP 132
__global__ __launch_bounds__(256) void gemm_pre(const float* __restrict__ x,
                                                const float* __restrict__ Win,
                                                const float* __restrict__ bin,
                                                float* __restrict__ pre) {
    __shared__ float As[BK][BMP];
    __shared__ float Bs[BK][BMP];
    const int tid = threadIdx.x;
    const int m0 = blockIdx.y * 128;
    const int n0 = blockIdx.x * 128;
    const int tx = tid & 15;
    const int ty = tid >> 4;
    float acc[8][8];
#pragma unroll
    for (int i = 0; i < 8; ++i)
#pragma unroll
        for (int j = 0; j < 8; ++j) acc[i][j] = 0.0f;
    const float* Aptr = x + (size_t)m0 * Dd;
    const float* Bptr = Win + (size_t)n0 * Dd;
    for (int k0 = 0; k0 < Dd; k0 += BK) {
#pragma unroll
        for (int i = 0; i < 2; ++i) {
            const int lin = tid + i * 256;
            const int row = lin >> 2;
            const int kq = (lin & 3) << 2;
            const float4 av = *(const float4*)(Aptr + (size_t)row * Dd + k0 + kq);
            const float4 bv = *(const float4*)(Bptr + (size_t)row * Dd + k0 + kq);
            As[kq + 0][row] = av.x; As[kq + 1][row] = av.y;
            As[kq + 2][row] = av.z; As[kq + 3][row] = av.w;
            Bs[kq + 0][row] = bv.x; Bs[kq + 1][row] = bv.y;
            Bs[kq + 2][row] = bv.z; Bs[kq + 3][row] = bv.w;
        }
        __syncthreads();
#pragma unroll
        for (int kk = 0; kk < BK; ++kk) {
            const float4 a0 = *(const float4*)&As[kk][ty * 4];
            const float4 a1 = *(const float4*)&As[kk][ty * 4 + 64];
            const float4 b0 = *(const float4*)&Bs[kk][tx * 4];
            const float4 b1 = *(const float4*)&Bs[kk][tx * 4 + 64];
            const float a[8] = {a0.x, a0.y, a0.z, a0.w, a1.x, a1.y, a1.z, a1.w};
            const float b[8] = {b0.x, b0.y, b0.z, b0.w, b1.x, b1.y, b1.z, b1.w};
#pragma unroll
            for (int i = 0; i < 8; ++i)
#pragma unroll
                for (int j = 0; j < 8; ++j) acc[i][j] += a[i] * b[j];
        }
        __syncthreads();
    }
#pragma unroll
    for (int i = 0; i < 8; ++i) {
        const int m = m0 + ((i < 4) ? (ty * 4 + i) : (64 + ty * 4 + i - 4));
#pragma unroll
        for (int half = 0; half < 2; ++half) {
            const int n = n0 + tx * 4 + half * 64;
            float4 v;
            v.x = acc[i][half * 4 + 0] + bin[n + 0];
            v.y = acc[i][half * 4 + 1] + bin[n + 1];
            v.z = acc[i][half * 4 + 2] + bin[n + 2];
            v.w = acc[i][half * 4 + 3] + bin[n + 3];
            *(float4*)(pre + (size_t)m * Hh + n) = v;
        }
    }
}

// ---------------------------------------------------------------------------
// Kernel 3: ALIF scan, 32-deep software-pipelined loads (32KB in flight/CU).
// ---------------------------------------------------------------------------
__global__ __launch_bounds__(256) void alif_scan(const float* __restrict__ pre,
                                                 const float* __restrict__ Wout,
                                                 float* __restrict__ partials) {
    const int h = blockIdx.x * 256 + threadIdx.x;
    const int b = blockIdx.y;
    const float* p = pre + (size_t)b * Tt * Hh + h;

    float buf[32];
#pragma unroll
    for (int j = 0; j < 32; ++j) buf[j] = p[(size_t)j * Hh];

    float mem = 0.0f, adapt = 0.0f, cnt = 0.0f;
    for (int t0 = 0; t0 < Tt; t0 += 32) {
        float cur[32];
#pragma unroll
        for (int j = 0; j < 32; ++j) cur[j] = buf[j];
        if (t0 + 32 < Tt) {
#pragma unroll
            for (int j = 0; j < 32; ++j) buf[j] = p[(size_t)(t0 + 32 + j) * Hh];
        }
#pragma unroll
        for (int j = 0; j < 32; ++j) {
            mem = 0.9f * mem + cur[j] - adapt;
            const float spk = (mem > 0.0f) ? 1.0f : 0.0f;
            adapt += 0.1f * spk;
            mem -= spk;
            cnt += spk;
        }
    }

    __shared__ float red[256];
    red[threadIdx.x] = cnt * Wout[h];
    __syncthreads();
#pragma unroll
    for (int s = 128; s > 0; s >>= 1) {
        if (threadIdx.x < s) red[threadIdx.x] += red[threadIdx.x + s];
        __syncthreads();
    }
    if (threadIdx.x == 0) partials[b * gridDim.x + blockIdx.x] = red[0];
}

__global__ void finalize(const float* __restrict__ partials,
                         const float* __restrict__ bout,
                         float* __restrict__ out, int nchunks) {
    const int b = threadIdx.x;
    float s = 0.0f;
    for (int c = 0; c < nchunks; ++c) s += partials[b * nchunks + c];
    out[b] = s * (1.0f / (float)Tt) + bout[0];
}

extern "C" void kernel_launch(void* const* d_in, const int* in_sizes, int n_in,
                              void* d_out, int out_size, void* d_ws, size_t ws_size,
                              hipStream_t stream) {
    const float* x    = (const float*)d_in[0];
    const float* Win  = (const float*)d_in[1];
    const float* bin  = (const float*)d_in[2];
    const float* Wout = (const float*)d_in[3];
    const float* bout = (const float*)d_in[4];
    float* out = (float*)d_out;

    const size_t pre_bytes = (size_t)Mm * Hh * 4;
    const size_t xh_bytes  = (size_t)Mm * Dd * 2;
    const size_t wh_bytes  = (size_t)Hh * Dd * 2;
    float* pre = (float*)d_ws;

    const size_t need = pre_bytes + 2 * xh_bytes + 2 * wh_bytes + 4096;
    if (ws_size >= need) {
        char* base = (char*)d_ws + pre_bytes;
        _Float16* xh = (_Float16*)base;
        _Float16* xl = (_Float16*)(base + xh_bytes);
        _Float16* wh = (_Float16*)(base + 2 * xh_bytes);
        _Float16* wl = (_Float16*)(base + 2 * xh_bytes + wh_bytes);
        float* partials = (float*)(base + 2 * xh_bytes + 2 * wh_bytes);

        // x: 256 row-tiles of 64; W: 16 row-tiles of 64. 8 k-tiles of 64.
        convert_t<<<dim3(8, 272), 256, 0, stream>>>(x, Win, xh, xl, wh, wl);

        dim3 g1(Hh / 128, Mm / 128);  // (8, 128)
        gemm_f16x2<<<g1, 256, 0, stream>>>(xh, xl, wh, wl, bin, pre);

        dim3 g2(Hh / 256, Bb);
        alif_scan<<<g2, 256, 0, stream>>>(pre, Wout, partials);
        finalize<<<1, 64, 0, stream>>>(partials, bout, out, Hh / 256);
    } else {
        float* partials = (float*)((char*)d_ws + pre_bytes);
        dim3 g1(Hh / 128, Mm / 128);
        gemm_pre<<<g1, 256, 0, stream>>>(x, Win, bin, pre);
        dim3 g2(Hh / 256, Bb);
        alif_scan<<<g2, 256, 0, stream>>>(pre, Wout, partials);
        finalize<<<1, 64, 0, stream>>>(partials, bout, out, Hh / 256);
    }
}

// Round 5
// 151.984 us; speedup vs baseline: 2.0171x; 1.0332x over previous
//
#include <hip/hip_runtime.h>

// Problem dims
constexpr int Bb = 64;     // batch
constexpr int Tt = 256;    // timesteps
constexpr int Dd = 512;    // input dim (K)
constexpr int Hh = 1024;   // hidden (N)
constexpr int Mm = Bb * Tt;  // 16384 GEMM rows

typedef _Float16 half8 __attribute__((ext_vector_type(8)));
typedef _Float16 half4v __attribute__((ext_vector_type(4)));
typedef float floatx16 __attribute__((ext_vector_type(16)));

#define GPTR(x) ((const __attribute__((address_space(1))) void*)(x))
#define LPTR(x) ((__attribute__((address_space(3))) void*)(x))

// ---------------------------------------------------------------------------
// Kernel 1: fp32 -> f16 hi/lo split, emitted CHUNK-TRANSPOSED: output chunk
// g = kc*nrows + row holds src[row][kc*8 .. kc*8+8) as 8 halves (16B), so the
// GEMM's global_load_lds staging is fully contiguous (1KB/instr).
// Also initializes out[b] = b_out (out is re-poisoned before every launch).
// ---------------------------------------------------------------------------
__global__ __launch_bounds__(256) void convert_t(const float* __restrict__ x,
                                                 const float* __restrict__ Win,
                                                 _Float16* __restrict__ xh,
                                                 _Float16* __restrict__ xl,
                                                 _Float16* __restrict__ wh,
                                                 _Float16* __restrict__ wl,
                                                 const float* __restrict__ bout,
                                                 float* __restrict__ out) {
    __shared__ _Float16 lh[64 * 72];
    __shared__ _Float16 ll[64 * 72];
    const int tid = threadIdx.x;
    const int k0 = blockIdx.x * 64;

    if (blockIdx.x == 0 && blockIdx.y == 0 && tid < Bb) out[tid] = bout[0];

    const float* src;
    _Float16 *dh, *dl;
    int nrows, m0;
    if (blockIdx.y < 256) {
        src = x; dh = xh; dl = xl; nrows = Mm; m0 = blockIdx.y * 64;
    } else {
        src = Win; dh = wh; dl = wl; nrows = Hh; m0 = (blockIdx.y - 256) * 64;
    }

#pragma unroll
    for (int i = 0; i < 4; ++i) {
        const int lin = tid + i * 256;
        const int row = lin >> 4;
        const int c4 = (lin & 15) * 4;
        const float4 v = *(const float4*)(src + (size_t)(m0 + row) * Dd + k0 + c4);
        const float va[4] = {v.x, v.y, v.z, v.w};
        half4v h, l;
#pragma unroll
        for (int q = 0; q < 4; ++q) {
            const _Float16 hi = (_Float16)va[q];
            h[q] = hi;
            l[q] = (_Float16)((va[q] - (float)hi) * 4096.0f);
        }
        *(half4v*)&lh[row * 72 + c4] = h;
        *(half4v*)&ll[row * 72 + c4] = l;
    }
    __syncthreads();
#pragma unroll
    for (int i = 0; i < 2; ++i) {
        const int lin = tid + i * 256;
        const int kc = lin >> 6;   // 0..7
        const int mm = lin & 63;
        const half8 h = *(const half8*)&lh[mm * 72 + kc * 8];
        const half8 l = *(const half8*)&ll[mm * 72 + kc * 8];
        const size_t g = (size_t)(k0 / 8 + kc) * nrows + m0 + mm;
        *(half8*)(dh + g * 8) = h;
        *(half8*)(dl + g * 8) = l;
    }
}

// ---------------------------------------------------------------------------
// Kernel 2: split-precision MFMA GEMM, BK=32, double-buffered LDS, with
// XCD-cooperative block remap: blocks sharing an A-tile run concurrently on
// ONE XCD (8 hot A-tiles x 512KB = 4MB = one L2), so A is fetched once
// device-wide instead of 8x. XCD = linear_block_id % 8 (heuristic, perf-only).
// ---------------------------------------------------------------------------
__global__ __launch_bounds__(256) void gemm_f16x2(const _Float16* __restrict__ xh,
                                                  const _Float16* __restrict__ xl,
                                                  const _Float16* __restrict__ wh,
                                                  const _Float16* __restrict__ wl,
                                                  const float* __restrict__ bin,
                                                  float* __restrict__ pre) {
    __shared__ _Float16 lds[2][4][4096];  // [buf][mat][512 chunks x 8 halves]

    const int tid = threadIdx.x;
    // Remap: XCD j owns m_tiles ≡ pattern 8*(s>>3)|j; n cycles fast within XCD.
    const int id = blockIdx.x;          // 0..1023
    const int j  = id & 7;              // XCD slot
    const int s  = id >> 3;             // 0..127
    const int m0 = (((s >> 3) << 3) | j) * 128;
    const int n0 = (s & 7) * 128;

    const int lane = tid & 63;
    const int wave = tid >> 6;
    const int wm = (wave & 1) * 64;
    const int wn = (wave >> 1) * 64;
    const int lr = lane & 31;
    const int lk = lane >> 5;

    floatx16 acc[2][2], accx[2][2];
#pragma unroll
    for (int mi = 0; mi < 2; ++mi)
#pragma unroll
        for (int ni = 0; ni < 2; ++ni)
#pragma unroll
            for (int r = 0; r < 16; ++r) { acc[mi][ni][r] = 0.0f; accx[mi][ni][r] = 0.0f; }

#define STAGE(buf, kc0)                                                              \
    do {                                                                             \
        _Pragma("unroll")                                                            \
        for (int i_ = 0; i_ < 2; ++i_) {                                             \
            const int c_ = tid + i_ * 256;                                           \
            const int kp_ = c_ >> 7;                                                 \
            const int row_ = c_ & 127;                                               \
            const size_t ga_ = ((size_t)((kc0) + kp_) * Mm + m0 + row_) * 8;         \
            const size_t gb_ = ((size_t)((kc0) + kp_) * Hh + n0 + row_) * 8;         \
            __builtin_amdgcn_global_load_lds(GPTR(xh + ga_), LPTR(&lds[buf][0][c_ * 8]), 16, 0, 0); \
            __builtin_amdgcn_global_load_lds(GPTR(xl + ga_), LPTR(&lds[buf][1][c_ * 8]), 16, 0, 0); \
            __builtin_amdgcn_global_load_lds(GPTR(wh + gb_), LPTR(&lds[buf][2][c_ * 8]), 16, 0, 0); \
            __builtin_amdgcn_global_load_lds(GPTR(wl + gb_), LPTR(&lds[buf][3][c_ * 8]), 16, 0, 0); \
        }                                                                            \
    } while (0)

    STAGE(0, 0);

    for (int ss = 0; ss < 16; ++ss) {
        __syncthreads();  // drains stage-ss loads; protects buf being overwritten
        if (ss < 15) STAGE((ss + 1) & 1, (ss + 1) * 4);
        const int cur = ss & 1;
#pragma unroll
        for (int s2 = 0; s2 < 2; ++s2) {
            half8 ah[2], al[2], bh[2], bl[2];
#pragma unroll
            for (int mi = 0; mi < 2; ++mi) {
                const int ci = (s2 * 2 + lk) * 128 + wm + mi * 32 + lr;
                ah[mi] = *(const half8*)&lds[cur][0][ci * 8];
                al[mi] = *(const half8*)&lds[cur][1][ci * 8];
            }
#pragma unroll
            for (int ni = 0; ni < 2; ++ni) {
                const int ci = (s2 * 2 + lk) * 128 + wn + ni * 32 + lr;
                bh[ni] = *(const half8*)&lds[cur][2][ci * 8];
                bl[ni] = *(const half8*)&lds[cur][3][ci * 8];
            }
#pragma unroll
            for (int mi = 0; mi < 2; ++mi)
#pragma unroll
                for (int ni = 0; ni < 2; ++ni) {
                    acc[mi][ni]  = __builtin_amdgcn_mfma_f32_32x32x16_f16(ah[mi], bh[ni], acc[mi][ni], 0, 0, 0);
                    accx[mi][ni] = __builtin_amdgcn_mfma_f32_32x32x16_f16(ah[mi], bl[ni], accx[mi][ni], 0, 0, 0);
                    accx[mi][ni] = __builtin_amdgcn_mfma_f32_32x32x16_f16(al[mi], bh[ni], accx[mi][ni], 0, 0, 0);
                }
        }
    }
#undef STAGE

    // Epilogue: C/D layout (32x32): col = lane&31, row = (r&3) + 8*(r>>2) + 4*(lane>>5)
    const float bv0 = bin[n0 + wn + lr];
    const float bv1 = bin[n0 + wn + 32 + lr];
#pragma unroll
    for (int mi = 0; mi < 2; ++mi)
#pragma unroll
        for (int ni = 0; ni < 2; ++ni) {
            const float bv = ni ? bv1 : bv0;
#pragma unroll
            for (int r = 0; r < 16; ++r) {
                const int row = (r & 3) + 8 * (r >> 2) + 4 * lk;
                const int m = m0 + wm + mi * 32 + row;
                const int n = n0 + wn + ni * 32 + lr;
                pre[(size_t)m * Hh + n] =
                    acc[mi][ni][r] + accx[mi][ni][r] * (1.0f / 4096.0f) + bv;
            }
        }
}

// ---------------------------------------------------------------------------
// Fallback fp32 SIMT GEMM (proven) in case ws is too small.
// ---------------------------------------------------------------------------
#define BK 16
#define BMP 132
__global__ __launch_bounds__(256) void gemm_pre(const float* __restrict__ x,
                                                const float* __restrict__ Win,
                                                const float* __restrict__ bin,
                                                float* __restrict__ pre) {
    __shared__ float As[BK][BMP];
    __shared__ float Bs[BK][BMP];
    const int tid = threadIdx.x;
    const int m0 = blockIdx.y * 128;
    const int n0 = blockIdx.x * 128;
    const int tx = tid & 15;
    const int ty = tid >> 4;
    float acc[8][8];
#pragma unroll
    for (int i = 0; i < 8; ++i)
#pragma unroll
        for (int jj = 0; jj < 8; ++jj) acc[i][jj] = 0.0f;
    const float* Aptr = x + (size_t)m0 * Dd;
    const float* Bptr = Win + (size_t)n0 * Dd;
    for (int k0 = 0; k0 < Dd; k0 += BK) {
#pragma unroll
        for (int i = 0; i < 2; ++i) {
            const int lin = tid + i * 256;
            const int row = lin >> 2;
            const int kq = (lin & 3) << 2;
            const float4 av = *(const float4*)(Aptr + (size_t)row * Dd + k0 + kq);
            const float4 bv = *(const float4*)(Bptr + (size_t)row * Dd + k0 + kq);
            As[kq + 0][row] = av.x; As[kq + 1][row] = av.y;
            As[kq + 2][row] = av.z; As[kq + 3][row] = av.w;
            Bs[kq + 0][row] = bv.x; Bs[kq + 1][row] = bv.y;
            Bs[kq + 2][row] = bv.z; Bs[kq + 3][row] = bv.w;
        }
        __syncthreads();
#pragma unroll
        for (int kk = 0; kk < BK; ++kk) {
            const float4 a0 = *(const float4*)&As[kk][ty * 4];
            const float4 a1 = *(const float4*)&As[kk][ty * 4 + 64];
            const float4 b0 = *(const float4*)&Bs[kk][tx * 4];
            const float4 b1 = *(const float4*)&Bs[kk][tx * 4 + 64];
            const float a[8] = {a0.x, a0.y, a0.z, a0.w, a1.x, a1.y, a1.z, a1.w};
            const float b[8] = {b0.x, b0.y, b0.z, b0.w, b1.x, b1.y, b1.z, b1.w};
#pragma unroll
            for (int i = 0; i < 8; ++i)
#pragma unroll
                for (int jj = 0; jj < 8; ++jj) acc[i][jj] += a[i] * b[jj];
        }
        __syncthreads();
    }
#pragma unroll
    for (int i = 0; i < 8; ++i) {
        const int m = m0 + ((i < 4) ? (ty * 4 + i) : (64 + ty * 4 + i - 4));
#pragma unroll
        for (int half = 0; half < 2; ++half) {
            const int n = n0 + tx * 4 + half * 64;
            float4 v;
            v.x = acc[i][half * 4 + 0] + bin[n + 0];
            v.y = acc[i][half * 4 + 1] + bin[n + 1];
            v.z = acc[i][half * 4 + 2] + bin[n + 2];
            v.w = acc[i][half * 4 + 3] + bin[n + 3];
            *(float4*)(pre + (size_t)m * Hh + n) = v;
        }
    }
}

__global__ __launch_bounds__(64) void init_out(const float* __restrict__ bout,
                                               float* __restrict__ out) {
    out[threadIdx.x] = bout[0];
}

// ---------------------------------------------------------------------------
// Kernel 3: ALIF scan, one wave per 64 h; 32-deep pipelined loads; wave-shuffle
// reduction; atomicAdd of the (already /T-scaled) partial into out[b].
// out[b] must be pre-initialized with b_out (done in convert_t / init_out).
// ---------------------------------------------------------------------------
__global__ __launch_bounds__(64) void alif_scan(const float* __restrict__ pre,
                                                const float* __restrict__ Wout,
                                                float* __restrict__ out) {
    const int h = blockIdx.x * 64 + threadIdx.x;
    const int b = blockIdx.y;
    const float* p = pre + (size_t)b * Tt * Hh + h;

    float buf[32];
#pragma unroll
    for (int jj = 0; jj < 32; ++jj) buf[jj] = p[(size_t)jj * Hh];

    float mem = 0.0f, adapt = 0.0f, cnt = 0.0f;
    for (int t0 = 0; t0 < Tt; t0 += 32) {
        float cur[32];
#pragma unroll
        for (int jj = 0; jj < 32; ++jj) cur[jj] = buf[jj];
        if (t0 + 32 < Tt) {
#pragma unroll
            for (int jj = 0; jj < 32; ++jj) buf[jj] = p[(size_t)(t0 + 32 + jj) * Hh];
        }
#pragma unroll
        for (int jj = 0; jj < 32; ++jj) {
            mem = 0.9f * mem + cur[jj] - adapt;
            const float spk = (mem > 0.0f) ? 1.0f : 0.0f;
            adapt += 0.1f * spk;
            mem -= spk;
            cnt += spk;
        }
    }

    float val = cnt * Wout[h] * (1.0f / (float)Tt);
#pragma unroll
    for (int off = 32; off > 0; off >>= 1) val += __shfl_down(val, off, 64);
    if (threadIdx.x == 0) atomicAdd(&out[b], val);
}

extern "C" void kernel_launch(void* const* d_in, const int* in_sizes, int n_in,
                              void* d_out, int out_size, void* d_ws, size_t ws_size,
                              hipStream_t stream) {
    const float* x    = (const float*)d_in[0];
    const float* Win  = (const float*)d_in[1];
    const float* bin  = (const float*)d_in[2];
    const float* Wout = (const float*)d_in[3];
    const float* bout = (const float*)d_in[4];
    float* out = (float*)d_out;

    const size_t pre_bytes = (size_t)Mm * Hh * 4;
    const size_t xh_bytes  = (size_t)Mm * Dd * 2;
    const size_t wh_bytes  = (size_t)Hh * Dd * 2;
    float* pre = (float*)d_ws;

    const size_t need = pre_bytes + 2 * xh_bytes + 2 * wh_bytes + 4096;
    if (ws_size >= need) {
        char* base = (char*)d_ws + pre_bytes;
        _Float16* xh = (_Float16*)base;
        _Float16* xl = (_Float16*)(base + xh_bytes);
        _Float16* wh = (_Float16*)(base + 2 * xh_bytes);
        _Float16* wl = (_Float16*)(base + 2 * xh_bytes + wh_bytes);

        // x: 256 row-tiles of 64; W: 16 row-tiles of 64. 8 k-tiles of 64.
        convert_t<<<dim3(8, 272), 256, 0, stream>>>(x, Win, xh, xl, wh, wl, bout, out);

        gemm_f16x2<<<1024, 256, 0, stream>>>(xh, xl, wh, wl, bin, pre);

        alif_scan<<<dim3(Hh / 64, Bb), 64, 0, stream>>>(pre, Wout, out);
    } else {
        init_out<<<1, 64, 0, stream>>>(bout, out);
        dim3 g1(Hh / 128, Mm / 128);
        gemm_pre<<<g1, 256, 0, stream>>>(x, Win, bin, pre);
        alif_scan<<<dim3(Hh / 64, Bb), 64, 0, stream>>>(pre, Wout, out);
    }
}